// Round 1
// baseline (482.330 us; speedup 1.0000x reference)
//
#include <hip/hip_runtime.h>

#define DD 768          // embedding dim
#define NT 192          // threads per block = DD/4 (float4 per thread), 3 waves
#define EPSF 1e-6f

__device__ inline float wave_reduce_sum(float v) {
    #pragma unroll
    for (int off = 32; off > 0; off >>= 1)
        v += __shfl_down(v, off, 64);
    return v;
}

// Kernel A: q_emb = mean(table1[q_ids], axis=0); ws[0..767] = q_emb, ws[768] = max(||q_emb||, eps)
__global__ void __launch_bounds__(NT) qemb_kernel(const float* __restrict__ table1,
                                                  const int* __restrict__ q_ids,
                                                  int LQ,
                                                  float* __restrict__ ws) {
    int tid = threadIdx.x;
    float4 acc = make_float4(0.f, 0.f, 0.f, 0.f);
    for (int i = 0; i < LQ; ++i) {
        const float4* row = reinterpret_cast<const float4*>(table1 + (long long)q_ids[i] * DD);
        float4 v = row[tid];
        acc.x += v.x; acc.y += v.y; acc.z += v.z; acc.w += v.w;
    }
    float inv = 1.0f / (float)LQ;
    acc.x *= inv; acc.y *= inv; acc.z *= inv; acc.w *= inv;
    reinterpret_cast<float4*>(ws)[tid] = acc;

    float n2 = acc.x * acc.x + acc.y * acc.y + acc.z * acc.z + acc.w * acc.w;
    n2 = wave_reduce_sum(n2);
    __shared__ float part[3];
    int wid = tid >> 6;
    if ((tid & 63) == 0) part[wid] = n2;
    __syncthreads();
    if (tid == 0) {
        float t = part[0] + part[1] + part[2];
        ws[DD] = fmaxf(sqrtf(t), EPSF);
    }
}

// Kernel B: one block per segment. Binary-search [lo,hi) in sorted cand_segments,
// accumulate the row-sum in registers (float4/thread), reduce dot & norm^2, emit cosine.
__global__ void __launch_bounds__(NT) segcos_kernel(const float* __restrict__ table2,
                                                    const int* __restrict__ cand_ids,
                                                    const int* __restrict__ segs,
                                                    int T,
                                                    const float* __restrict__ ws,
                                                    float* __restrict__ out) {
    int n = blockIdx.x;
    int tid = threadIdx.x;

    // lower_bound(segs, n) and lower_bound(segs, n+1) — uniform across the block.
    int lo, hi;
    {
        int l = 0, r = T;
        while (l < r) { int m = (l + r) >> 1; if (segs[m] < n) l = m + 1; else r = m; }
        lo = l;
        r = T;
        while (l < r) { int m = (l + r) >> 1; if (segs[m] <= n) l = m + 1; else r = m; }
        hi = l;
    }

    float4 q = reinterpret_cast<const float4*>(ws)[tid];
    float qn = ws[DD];

    float4 acc = make_float4(0.f, 0.f, 0.f, 0.f);
    for (int i = lo; i < hi; ++i) {
        const float4* row = reinterpret_cast<const float4*>(table2 + (long long)cand_ids[i] * DD);
        float4 v = row[tid];
        acc.x += v.x; acc.y += v.y; acc.z += v.z; acc.w += v.w;
    }

    float dot = acc.x * q.x + acc.y * q.y + acc.z * q.z + acc.w * q.w;
    float n2  = acc.x * acc.x + acc.y * acc.y + acc.z * acc.z + acc.w * acc.w;
    dot = wave_reduce_sum(dot);
    n2  = wave_reduce_sum(n2);

    __shared__ float pd[3], pn[3];
    int wid = tid >> 6;
    if ((tid & 63) == 0) { pd[wid] = dot; pn[wid] = n2; }
    __syncthreads();
    if (tid == 0) {
        float sdot = pd[0] + pd[1] + pd[2];
        float sn2  = pn[0] + pn[1] + pn[2];
        float cnt  = (float)(hi - lo);
        float c    = fmaxf(cnt, 1.0f);           // max(counts, 1)
        float cd   = sdot / c;                    // cand_emb . q_emb
        float cn   = fmaxf(sqrtf(sn2) / c, EPSF); // max(||cand_emb||, eps)
        out[n] = cd / (qn * cn);
    }
}

extern "C" void kernel_launch(void* const* d_in, const int* in_sizes, int n_in,
                              void* d_out, int out_size, void* d_ws, size_t ws_size,
                              hipStream_t stream) {
    const float* table1   = (const float*)d_in[0];
    const float* table2   = (const float*)d_in[1];
    const int*   q_ids    = (const int*)d_in[2];
    const int*   cand_ids = (const int*)d_in[3];
    const int*   segs     = (const int*)d_in[4];
    // d_in[5] = num_candidates scalar; N == out_size (1 x N output)

    int LQ = in_sizes[2];
    int T  = in_sizes[3];
    int N  = out_size;

    float* ws  = (float*)d_ws;   // [0..767] q_emb, [768] q_norm
    float* out = (float*)d_out;

    qemb_kernel<<<1, NT, 0, stream>>>(table1, q_ids, LQ, ws);
    segcos_kernel<<<N, NT, 0, stream>>>(table2, cand_ids, segs, T, ws, out);
}

// Round 2
// 478.174 us; speedup vs baseline: 1.0087x; 1.0087x over previous
//
#include <hip/hip_runtime.h>

#define DD 768          // embedding dim
#define EPSF 1e-6f

// ---------------- Kernel A: q_emb + q_norm into ws[0..768] ----------------
__global__ void __launch_bounds__(192) qemb_kernel(const float* __restrict__ table1,
                                                   const int* __restrict__ q_ids,
                                                   int LQ,
                                                   float* __restrict__ ws) {
    int tid = threadIdx.x;
    float4 acc = make_float4(0.f, 0.f, 0.f, 0.f);
    for (int i = 0; i < LQ; ++i) {
        const float4* row = reinterpret_cast<const float4*>(table1 + (long long)q_ids[i] * DD);
        float4 v = row[tid];
        acc.x += v.x; acc.y += v.y; acc.z += v.z; acc.w += v.w;
    }
    float inv = 1.0f / (float)LQ;
    acc.x *= inv; acc.y *= inv; acc.z *= inv; acc.w *= inv;
    reinterpret_cast<float4*>(ws)[tid] = acc;

    float n2 = acc.x * acc.x + acc.y * acc.y + acc.z * acc.z + acc.w * acc.w;
    #pragma unroll
    for (int off = 32; off > 0; off >>= 1) n2 += __shfl_down(n2, off, 64);
    __shared__ float part[3];
    int wid = tid >> 6;
    if ((tid & 63) == 0) part[wid] = n2;
    __syncthreads();
    if (tid == 0) {
        float t = part[0] + part[1] + part[2];
        ws[DD] = fmaxf(sqrtf(t), EPSF);
    }
}

// ------------- Kernel S: starts[n] = lower_bound(segs, n), n in [0, N] -------------
// segs is sorted; thread i covers the value gap (segs[i-1], segs[i]].
__global__ void __launch_bounds__(256) starts_kernel(const int* __restrict__ segs,
                                                     int T, int N,
                                                     int* __restrict__ starts) {
    int i = blockIdx.x * blockDim.x + threadIdx.x;
    if (i > T) return;
    int prev = (i > 0) ? segs[i - 1] : -1;
    int cur  = (i < T) ? segs[i]     : N;
    for (int n = prev + 1; n <= cur; ++n) starts[n] = i;
}

// ------------- Kernel B: one WAVE per segment, 4 segments per 256-thread block -------------
#define ACC4(A, V) do { A.x += V.x; A.y += V.y; A.z += V.z; A.w += V.w; } while (0)

__global__ void __launch_bounds__(256) segcos_kernel(const float* __restrict__ table2,
                                                     const int* __restrict__ cand_ids,
                                                     const int* __restrict__ starts,
                                                     const float* __restrict__ ws,
                                                     float* __restrict__ out,
                                                     int N) {
    int tid  = threadIdx.x;
    int lane = tid & 63;
    int n    = blockIdx.x * 4 + (tid >> 6);
    if (n >= N) return;

    int lo = starts[n];
    int hi = starts[n + 1];

    const float4* Q = reinterpret_cast<const float4*>(ws);
    float4 q0 = Q[lane], q1 = Q[lane + 64], q2 = Q[lane + 128];
    float  qn = ws[DD];

    float4 a0 = make_float4(0.f,0.f,0.f,0.f);
    float4 a1 = make_float4(0.f,0.f,0.f,0.f);
    float4 a2 = make_float4(0.f,0.f,0.f,0.f);

    int i = lo;
    for (; i + 2 <= hi; i += 2) {
        long long id0 = cand_ids[i];
        long long id1 = cand_ids[i + 1];
        const float4* r0 = reinterpret_cast<const float4*>(table2 + id0 * DD);
        const float4* r1 = reinterpret_cast<const float4*>(table2 + id1 * DD);
        float4 x0 = r0[lane], x1 = r0[lane + 64], x2 = r0[lane + 128];
        float4 y0 = r1[lane], y1 = r1[lane + 64], y2 = r1[lane + 128];
        ACC4(a0, x0); ACC4(a1, x1); ACC4(a2, x2);
        ACC4(a0, y0); ACC4(a1, y1); ACC4(a2, y2);
    }
    if (i < hi) {
        long long id0 = cand_ids[i];
        const float4* r0 = reinterpret_cast<const float4*>(table2 + id0 * DD);
        float4 x0 = r0[lane], x1 = r0[lane + 64], x2 = r0[lane + 128];
        ACC4(a0, x0); ACC4(a1, x1); ACC4(a2, x2);
    }

    float dot = a0.x*q0.x + a0.y*q0.y + a0.z*q0.z + a0.w*q0.w
              + a1.x*q1.x + a1.y*q1.y + a1.z*q1.z + a1.w*q1.w
              + a2.x*q2.x + a2.y*q2.y + a2.z*q2.z + a2.w*q2.w;
    float n2  = a0.x*a0.x + a0.y*a0.y + a0.z*a0.z + a0.w*a0.w
              + a1.x*a1.x + a1.y*a1.y + a1.z*a1.z + a1.w*a1.w
              + a2.x*a2.x + a2.y*a2.y + a2.z*a2.z + a2.w*a2.w;
    #pragma unroll
    for (int off = 32; off > 0; off >>= 1) {
        dot += __shfl_down(dot, off, 64);
        n2  += __shfl_down(n2,  off, 64);
    }
    if (lane == 0) {
        float cnt = (float)(hi - lo);
        float c   = fmaxf(cnt, 1.0f);             // max(counts, 1)
        float cn  = fmaxf(sqrtf(n2) / c, EPSF);   // max(||cand_emb||, eps)
        out[n] = (dot / c) / (qn * cn);
    }
}

extern "C" void kernel_launch(void* const* d_in, const int* in_sizes, int n_in,
                              void* d_out, int out_size, void* d_ws, size_t ws_size,
                              hipStream_t stream) {
    const float* table1   = (const float*)d_in[0];
    const float* table2   = (const float*)d_in[1];
    const int*   q_ids    = (const int*)d_in[2];
    const int*   cand_ids = (const int*)d_in[3];
    const int*   segs     = (const int*)d_in[4];

    int LQ = in_sizes[2];
    int T  = in_sizes[3];
    int N  = out_size;

    float* ws     = (float*)d_ws;                    // [0..767] q_emb, [768] q_norm
    int*   starts = (int*)((char*)d_ws + 4096);      // [N+1] segment starts
    float* out    = (float*)d_out;

    qemb_kernel<<<1, 192, 0, stream>>>(table1, q_ids, LQ, ws);
    starts_kernel<<<(T + 1 + 255) / 256, 256, 0, stream>>>(segs, T, N, starts);
    segcos_kernel<<<(N + 3) / 4, 256, 0, stream>>>(table2, cand_ids, starts, ws, out, N);
}

// Round 4
// 464.767 us; speedup vs baseline: 1.0378x; 1.0288x over previous
//
#include <hip/hip_runtime.h>

#define DD 768          // embedding dim
#define EPSF 1e-6f

#define ACC4(A, V) do { A.x += V.x; A.y += V.y; A.z += V.z; A.w += V.w; } while (0)

// ---- Merged prep kernel ----
// block 0           : q_emb = mean(table1[q_ids]) -> ws[0..767], ws[768] = max(||q_emb||, eps)
// blocks 1..        : starts[n] = lower_bound(segs, n) for n in [0, N]
__global__ void __launch_bounds__(256) prep_kernel(const float* __restrict__ table1,
                                                   const int* __restrict__ q_ids,
                                                   int LQ,
                                                   const int* __restrict__ segs,
                                                   int T, int N,
                                                   float* __restrict__ ws,
                                                   int* __restrict__ starts) {
    int tid = threadIdx.x;
    if (blockIdx.x == 0) {
        __shared__ float part[3];
        float4 acc = make_float4(0.f, 0.f, 0.f, 0.f);
        if (tid < 192) {
            float4 a0 = make_float4(0.f,0.f,0.f,0.f);
            float4 a1 = make_float4(0.f,0.f,0.f,0.f);
            float4 a2 = make_float4(0.f,0.f,0.f,0.f);
            float4 a3 = make_float4(0.f,0.f,0.f,0.f);
            int i = 0;
            for (; i + 4 <= LQ; i += 4) {   // 4 independent rows in flight
                const float4* r0 = reinterpret_cast<const float4*>(table1 + (long long)q_ids[i]   * DD);
                const float4* r1 = reinterpret_cast<const float4*>(table1 + (long long)q_ids[i+1] * DD);
                const float4* r2 = reinterpret_cast<const float4*>(table1 + (long long)q_ids[i+2] * DD);
                const float4* r3 = reinterpret_cast<const float4*>(table1 + (long long)q_ids[i+3] * DD);
                float4 v0 = r0[tid], v1 = r1[tid], v2 = r2[tid], v3 = r3[tid];
                ACC4(a0, v0); ACC4(a1, v1); ACC4(a2, v2); ACC4(a3, v3);
            }
            for (; i < LQ; ++i) {
                const float4* r0 = reinterpret_cast<const float4*>(table1 + (long long)q_ids[i] * DD);
                float4 v0 = r0[tid];
                ACC4(a0, v0);
            }
            ACC4(a0, a1); ACC4(a2, a3); ACC4(a0, a2);
            float inv = 1.0f / (float)LQ;
            a0.x *= inv; a0.y *= inv; a0.z *= inv; a0.w *= inv;
            reinterpret_cast<float4*>(ws)[tid] = a0;
            acc = a0;
        }
        float n2 = acc.x*acc.x + acc.y*acc.y + acc.z*acc.z + acc.w*acc.w;
        #pragma unroll
        for (int off = 32; off > 0; off >>= 1) n2 += __shfl_down(n2, off, 64);
        int wid = tid >> 6;
        if (wid < 3 && (tid & 63) == 0) part[wid] = n2;
        __syncthreads();
        if (tid == 0) {
            float t = part[0] + part[1] + part[2];
            ws[DD] = fmaxf(sqrtf(t), EPSF);
        }
    } else {
        int i = (blockIdx.x - 1) * 256 + tid;
        if (i <= T) {
            int prev = (i > 0) ? segs[i - 1] : -1;
            int cur  = (i < T) ? segs[i]     : N;
            for (int n = prev + 1; n <= cur; ++n) starts[n] = i;
        }
    }
}

// ---- Kernel B: one WAVE per segment, 4 segments per 256-thread block ----
// unroll-4 row gather, two accumulator sets for MLP + shorter fadd chains.
__global__ void __launch_bounds__(256) segcos_kernel(const float* __restrict__ table2,
                                                     const int* __restrict__ cand_ids,
                                                     const int* __restrict__ starts,
                                                     const float* __restrict__ ws,
                                                     float* __restrict__ out,
                                                     int N) {
    int tid  = threadIdx.x;
    int lane = tid & 63;
    int n    = blockIdx.x * 4 + (tid >> 6);
    if (n >= N) return;

    int lo = starts[n];
    int hi = starts[n + 1];

    const float4* Q = reinterpret_cast<const float4*>(ws);
    float4 q0 = Q[lane], q1 = Q[lane + 64], q2 = Q[lane + 128];
    float  qn = ws[DD];

    float4 a0 = make_float4(0.f,0.f,0.f,0.f);
    float4 a1 = make_float4(0.f,0.f,0.f,0.f);
    float4 a2 = make_float4(0.f,0.f,0.f,0.f);
    float4 b0 = make_float4(0.f,0.f,0.f,0.f);
    float4 b1 = make_float4(0.f,0.f,0.f,0.f);
    float4 b2 = make_float4(0.f,0.f,0.f,0.f);

    int i = lo;
    for (; i + 4 <= hi; i += 4) {
        long long id0 = cand_ids[i];
        long long id1 = cand_ids[i + 1];
        long long id2 = cand_ids[i + 2];
        long long id3 = cand_ids[i + 3];
        const float4* r0 = reinterpret_cast<const float4*>(table2 + id0 * DD);
        const float4* r1 = reinterpret_cast<const float4*>(table2 + id1 * DD);
        const float4* r2 = reinterpret_cast<const float4*>(table2 + id2 * DD);
        const float4* r3 = reinterpret_cast<const float4*>(table2 + id3 * DD);
        float4 x0 = r0[lane], x1 = r0[lane + 64], x2 = r0[lane + 128];
        float4 y0 = r1[lane], y1 = r1[lane + 64], y2 = r1[lane + 128];
        float4 z0 = r2[lane], z1 = r2[lane + 64], z2 = r2[lane + 128];
        float4 w0 = r3[lane], w1 = r3[lane + 64], w2 = r3[lane + 128];
        ACC4(a0, x0); ACC4(a1, x1); ACC4(a2, x2);
        ACC4(b0, y0); ACC4(b1, y1); ACC4(b2, y2);
        ACC4(a0, z0); ACC4(a1, z1); ACC4(a2, z2);
        ACC4(b0, w0); ACC4(b1, w1); ACC4(b2, w2);
    }
    for (; i < hi; ++i) {
        long long id0 = cand_ids[i];
        const float4* r0 = reinterpret_cast<const float4*>(table2 + id0 * DD);
        float4 x0 = r0[lane], x1 = r0[lane + 64], x2 = r0[lane + 128];
        ACC4(a0, x0); ACC4(a1, x1); ACC4(a2, x2);
    }
    ACC4(a0, b0); ACC4(a1, b1); ACC4(a2, b2);

    float dot = a0.x*q0.x + a0.y*q0.y + a0.z*q0.z + a0.w*q0.w
              + a1.x*q1.x + a1.y*q1.y + a1.z*q1.z + a1.w*q1.w
              + a2.x*q2.x + a2.y*q2.y + a2.z*q2.z + a2.w*q2.w;
    float n2  = a0.x*a0.x + a0.y*a0.y + a0.z*a0.z + a0.w*a0.w
              + a1.x*a1.x + a1.y*a1.y + a1.z*a1.z + a1.w*a1.w
              + a2.x*a2.x + a2.y*a2.y + a2.z*a2.z + a2.w*a2.w;
    #pragma unroll
    for (int off = 32; off > 0; off >>= 1) {
        dot += __shfl_down(dot, off, 64);
        n2  += __shfl_down(n2,  off, 64);
    }
    if (lane == 0) {
        float cnt = (float)(hi - lo);
        float c   = fmaxf(cnt, 1.0f);             // max(counts, 1)
        float cn  = fmaxf(sqrtf(n2) / c, EPSF);   // max(||cand_emb||, eps)
        out[n] = (dot / c) / (qn * cn);
    }
}

extern "C" void kernel_launch(void* const* d_in, const int* in_sizes, int n_in,
                              void* d_out, int out_size, void* d_ws, size_t ws_size,
                              hipStream_t stream) {
    const float* table1   = (const float*)d_in[0];
    const float* table2   = (const float*)d_in[1];
    const int*   q_ids    = (const int*)d_in[2];
    const int*   cand_ids = (const int*)d_in[3];
    const int*   segs     = (const int*)d_in[4];

    int LQ = in_sizes[2];
    int T  = in_sizes[3];
    int N  = out_size;

    float* ws     = (float*)d_ws;                    // [0..767] q_emb, [768] q_norm
    int*   starts = (int*)((char*)d_ws + 4096);      // [N+1] segment starts
    float* out    = (float*)d_out;

    int prep_blocks = 1 + (T + 1 + 255) / 256;       // block 0 = qemb, rest = starts
    prep_kernel<<<prep_blocks, 256, 0, stream>>>(table1, q_ids, LQ, segs, T, N, ws, starts);
    segcos_kernel<<<(N + 3) / 4, 256, 0, stream>>>(table2, cand_ids, starts, ws, out, N);
}